// Round 7
// baseline (198.423 us; speedup 1.0000x reference)
//
#include <hip/hip_runtime.h>
#include <hip/hip_cooperative_groups.h>

namespace cg = cooperative_groups;

#define NPTS 2048
#define CH 32
#define KT 40                 // Taylor terms
#define NBLK 128
#define NTHR 512
#define RPB 16                // rows per block
#define LOG2E 1.4426950408889634f

#if defined(__has_builtin)
#if __has_builtin(__builtin_amdgcn_exp2f)
#define EXP2F(x) __builtin_amdgcn_exp2f(x)
#endif
#endif
#ifndef EXP2F
#define EXP2F(x) exp2f(x)
#endif

struct Params {
    const float *f_x, *x_grid, *qw, *lift_W, *lift_b, *pw_W, *pw_b, *kle, *kls;
    const float *p1W, *p1b, *p2W, *p2b, *p3W, *p3b;
    float* P;                 // [NBLK][KT*CH] partial moments (workspace)
    float* out;
};

__device__ __forceinline__ float gelu_tanh(float x) {
    float x3 = x * x * x;
    float u = 0.7978845608028654f * (x + 0.044715f * x3);
    return 0.5f * x * (1.0f + tanhf(u));
}

// One block owns RPB=16 grid rows (which are also 16 quadrature points).
// fq never leaves LDS; only 1280-float moment partials cross blocks.
__global__ __launch_bounds__(NTHR) void k_fused(Params p) {
    __shared__ float sWt[3][CH][CH];          // pw_W transposed [l][k][c]
    __shared__ float sW1t[CH][CH], sW2t[CH][CH];
    __shared__ float sb1[CH], sb2[CH], sW3[CH];
    __shared__ float xrow[RPB], wrow[RPB], fxrow[RPB];
    __shared__ float lgk[KT];                 // log2(k!)
    __shared__ float fqb[2][RPB][CH];         // double-buffered feature rows
    __shared__ float sS[RPB][CH], sLT[RPB][CH];
    __shared__ float sM[KT][CH];

    const int tid = threadIdx.x;
    const int b = blockIdx.x;
    const int r = tid >> 5, c = tid & 31;
    const int n0 = b * RPB;
    cg::grid_group grid = cg::this_grid();

    // ---- preload ----
    for (int i = tid; i < 3 * CH * CH; i += NTHR) {
        const int l = i >> 10, k = (i >> 5) & 31, cc = i & 31;
        sWt[l][k][cc] = p.pw_W[l * CH * CH + cc * CH + k];
    }
    for (int i = tid; i < CH * CH; i += NTHR) {
        const int k = i >> 5, cc = i & 31;
        sW1t[k][cc] = p.p1W[cc * CH + k];
        sW2t[k][cc] = p.p2W[cc * CH + k];
    }
    if (tid < CH) { sb1[tid] = p.p1b[tid]; sb2[tid] = p.p2b[tid]; sW3[tid] = p.p3W[tid]; }
    if (tid < RPB) {
        xrow[tid] = p.x_grid[n0 + tid];
        wrow[tid] = p.qw[n0 + tid];
        fxrow[tid] = p.f_x[n0 + tid];
    }
    if (tid < KT) lgk[tid] = lgammaf((float)tid + 1.0f) * LOG2E;
    __syncthreads();

    // ---- lift (row-local) ----
    {
        float v = fxrow[r] * p.lift_W[c * 2] + xrow[r] * p.lift_W[c * 2 + 1] + p.lift_b[c];
        fqb[0][r][c] = gelu_tanh(v);
    }

    int cur = 0;
    const int kk = tid >> 5;                  // 0..15: k-slot for moment phases

    for (int l = 0; l < 3; l++) {
        const float invl2 = expf(-2.0f * p.kle[l * CH + c]);
        const float nb2 = -0.5f * invl2 * LOG2E;     // exp2(x^2*nb2) = e^{-x^2/(2 ell^2)}
        const float sig2 = expf(2.0f * p.kls[l * CH + c]);
        __syncthreads();                      // fqb[cur] ready

        // stage A: per (row, channel) helpers
        {
            const float xq = xrow[r];
            sS[r][c] = EXP2F(xq * xq * nb2) * fqb[cur][r][c] * wrow[r];
            sLT[r][c] = log2f(xq * invl2);    // log2(t), t = xq/ell^2 > 0
        }
        __syncthreads();

        // stage B: block-partial moments, k in {kk, kk+16, kk+32 (kk<8)}
        {
            float a0 = 0.f, a1 = 0.f, a2 = 0.f;
            const float l0 = lgk[kk], l1 = lgk[kk + 16], l2 = (kk < 8) ? lgk[kk + 32] : 0.f;
#pragma unroll
            for (int rr = 0; rr < RPB; rr++) {
                const float s = sS[rr][c], lt = sLT[rr][c];
                a0 += (kk == 0) ? s : EXP2F(fmaf((float)kk, lt, -l0)) * s;
                a1 += EXP2F(fmaf((float)(kk + 16), lt, -l1)) * s;
                if (kk < 8) a2 += EXP2F(fmaf((float)(kk + 32), lt, -l2)) * s;
            }
            float* Pb = p.P + b * (KT * CH);
            Pb[kk * CH + c] = a0;
            Pb[(kk + 16) * CH + c] = a1;
            if (kk < 8) Pb[(kk + 32) * CH + c] = a2;
        }
        grid.sync();                          // all partials visible

        // stage C: every block redundantly reduces all partials (deterministic)
        {
            float a0 = 0.f, a1 = 0.f, a2 = 0.f;
#pragma unroll 8
            for (int b2 = 0; b2 < NBLK; b2++) {
                const float* Pb = p.P + b2 * (KT * CH);
                a0 += Pb[kk * CH + c];
                a1 += Pb[(kk + 16) * CH + c];
                if (kk < 8) a2 += Pb[(kk + 32) * CH + c];
            }
            sM[kk][c] = a0;
            sM[kk + 16][c] = a1;
            if (kk < 8) sM[kk + 32][c] = a2;
        }
        if (l < 2) grid.sync();               // WAR guard: P rewritten next layer
        __syncthreads();

        // stage D: apply (row-local): integ + skip GEMM (+ gelu)
        {
            const float xn = xrow[r];
            float Ph = sM[KT - 1][c];
#pragma unroll
            for (int k = KT - 2; k >= 0; k--) Ph = fmaf(Ph, xn, sM[k][c]);
            const float integ = sig2 * EXP2F(xn * xn * nb2) * Ph;
            float skip = p.pw_b[l * CH + c];
#pragma unroll
            for (int k = 0; k < CH; k++) skip = fmaf(fqb[cur][r][k], sWt[l][k][c], skip);
            float v = skip + integ;
            if (l < 2) v = gelu_tanh(v);
            fqb[cur ^ 1][r][c] = v;
        }
        cur ^= 1;
    }
    __syncthreads();

    // ---- projection head (row-local; reuse sS/sLT as h1/h2) ----
    {
        float s = sb1[c];
#pragma unroll
        for (int k = 0; k < CH; k++) s = fmaf(fqb[cur][r][k], sW1t[k][c], s);
        sS[r][c] = gelu_tanh(s);
    }
    __syncthreads();
    {
        float s = sb2[c];
#pragma unroll
        for (int k = 0; k < CH; k++) s = fmaf(sS[r][k], sW2t[k][c], s);
        sLT[r][c] = gelu_tanh(s);
    }
    __syncthreads();
    if (tid < RPB) {
        float s = p.p3b[0];
#pragma unroll
        for (int k = 0; k < CH; k++) s = fmaf(sLT[tid][k], sW3[k], s);
        p.out[n0 + tid] = s;
    }
}

extern "C" void kernel_launch(void* const* d_in, const int* in_sizes, int n_in,
                              void* d_out, int out_size, void* d_ws, size_t ws_size,
                              hipStream_t stream) {
    Params p;
    p.f_x    = (const float*)d_in[0];
    p.x_grid = (const float*)d_in[1];
    p.qw     = (const float*)d_in[2];
    p.lift_W = (const float*)d_in[3];
    p.lift_b = (const float*)d_in[4];
    p.pw_W   = (const float*)d_in[5];
    p.pw_b   = (const float*)d_in[6];
    p.kle    = (const float*)d_in[7];
    p.kls    = (const float*)d_in[8];
    p.p1W    = (const float*)d_in[9];
    p.p1b    = (const float*)d_in[10];
    p.p2W    = (const float*)d_in[11];
    p.p2b    = (const float*)d_in[12];
    p.p3W    = (const float*)d_in[13];
    p.p3b    = (const float*)d_in[14];
    p.P      = (float*)d_ws;
    p.out    = (float*)d_out;

    void* args[] = { &p };
    hipLaunchCooperativeKernel(k_fused, dim3(NBLK), dim3(NTHR), args, 0, stream);
}

// Round 8
// 49.597 us; speedup vs baseline: 4.0007x; 4.0007x over previous
//
#include <hip/hip_runtime.h>

#define NPTS 2048
#define CH 32
#define KT 32                 // Taylor terms (t <= ~14 -> tail < 1e-5)
#define NBLK 64
#define NTHR 512
#define RPB 32                // rows per block
#define LOG2E 1.4426950408889634f

#if defined(__has_builtin)
#if __has_builtin(__builtin_amdgcn_exp2f)
#define EXP2F(x) __builtin_amdgcn_exp2f(x)
#endif
#endif
#ifndef EXP2F
#define EXP2F(x) exp2f(x)
#endif

struct Params {
    const float *f_x, *x_grid, *qw, *lift_W, *lift_b, *pw_W, *pw_b, *kle, *kls;
    const float *p1W, *p1b, *p2W, *p2b, *p3W, *p3b;
    int* ctrl;                // 3 one-shot barrier counters (memset to 0 per call)
    float* P;                 // 2 ping-pong partial buffers [2][NBLK][KT*CH]
    float* out;
};

__device__ __forceinline__ float gelu_tanh(float x) {
    float x3 = x * x * x;
    float u = 0.7978845608028654f * (x + 0.044715f * x3);
    return 0.5f * x * (1.0f + tanhf(u));
}

// Device-scope one-shot barrier: block arrives (release), spins until all NBLK arrived.
__device__ __forceinline__ void gbar(int* cnt) {
    __syncthreads();                       // all waves' global stores drained (vmcnt0 before barrier)
    if (threadIdx.x == 0) {
        __threadfence();                   // agent release: write back L2 so partials reach L3
        __hip_atomic_fetch_add(cnt, 1, __ATOMIC_RELEASE, __HIP_MEMORY_SCOPE_AGENT);
        while (__hip_atomic_load(cnt, __ATOMIC_ACQUIRE, __HIP_MEMORY_SCOPE_AGENT) < NBLK)
            __builtin_amdgcn_s_sleep(2);
    }
    __syncthreads();
}

__global__ __launch_bounds__(NTHR, 1) void k_fused(Params p) {
    __shared__ float sWt[3][CH][CH];       // pw_W transposed [l][k][c]
    __shared__ float sW1t[CH][CH], sW2t[CH][CH];
    __shared__ float sb1[CH], sb2[CH], sW3v[CH];
    __shared__ float xrow[RPB], wrow[RPB];
    __shared__ float lgk[KT];              // log2(k!)
    __shared__ float fqb[2][RPB][CH];
    __shared__ float sS[RPB][CH], sLT[RPB][CH];
    __shared__ float sM[KT][CH];

    const int tid = threadIdx.x;
    const int b = blockIdx.x;
    const int c = tid & 31;
    const int r0 = tid >> 5;               // 0..15; this thread covers rows r0 and r0+16
    const int n0 = b * RPB;

    // ---- preload ----
    for (int i = tid; i < 3 * CH * CH; i += NTHR) {
        const int l = i >> 10, k = (i >> 5) & 31, cc = i & 31;
        sWt[l][k][cc] = p.pw_W[l * CH * CH + cc * CH + k];
    }
    for (int i = tid; i < CH * CH; i += NTHR) {
        const int k = i >> 5, cc = i & 31;
        sW1t[k][cc] = p.p1W[cc * CH + k];
        sW2t[k][cc] = p.p2W[cc * CH + k];
    }
    if (tid < CH) { sb1[tid] = p.p1b[tid]; sb2[tid] = p.p2b[tid]; sW3v[tid] = p.p3W[tid]; }
    if (tid < KT) lgk[tid] = lgammaf((float)tid + 1.0f) * LOG2E;
    if (tid < RPB) { xrow[tid] = p.x_grid[n0 + tid]; wrow[tid] = p.qw[n0 + tid]; }
    __syncthreads();

    // ---- lift (row-local) ----
    for (int rr = r0; rr < RPB; rr += 16) {
        float v = p.f_x[n0 + rr] * p.lift_W[c * 2] + xrow[rr] * p.lift_W[c * 2 + 1] + p.lift_b[c];
        fqb[0][rr][c] = gelu_tanh(v);
    }

    int cur = 0;
    for (int l = 0; l < 3; l++) {
        const float invl2 = expf(-2.0f * p.kle[l * CH + c]);
        const float nb2 = -0.5f * invl2 * LOG2E;   // exp2(x^2*nb2) = e^{-x^2/(2 ell^2)}
        const float sig2 = expf(2.0f * p.kls[l * CH + c]);
        __syncthreads();                   // fqb[cur] ready for all threads

        // stage A: s = e^{-xq^2/(2l^2)} * fq * w ;  lt = log2(xq/ell^2)
        for (int rr = r0; rr < RPB; rr += 16) {
            const float xq = xrow[rr];
            sS[rr][c] = EXP2F(xq * xq * nb2) * fqb[cur][rr][c] * wrow[rr];
            sLT[rr][c] = log2f(fmaxf(xq, 1e-30f) * invl2);
        }
        __syncthreads();

        // stage B: block-partial moments  Pb[k*CH+c] = sum_r exp2(k*lt - lg k!) * s
        float* Pb = p.P + (l & 1) * (NBLK * KT * CH) + b * (KT * CH);
        for (int it = tid; it < KT * CH; it += NTHR) {
            const int k = it >> 5, cc = it & 31;
            const float kf = (float)k, nl = -lgk[k];
            float a = 0.0f;
#pragma unroll
            for (int rr = 0; rr < RPB; rr++)
                a += EXP2F(fmaf(kf, sLT[rr][cc], nl)) * sS[rr][cc];
            Pb[it] = a;
        }

        gbar(p.ctrl + l);                  // all partials visible device-wide

        // stage C: every block reduces all partials (deterministic order, L2-bypass loads)
        {
            float* P0 = p.P + (l & 1) * (NBLK * KT * CH);
            for (int it = tid; it < KT * CH; it += NTHR) {
                float a = 0.0f;
                for (int b2 = 0; b2 < NBLK; b2++)
                    a += __hip_atomic_load(P0 + b2 * (KT * CH) + it,
                                           __ATOMIC_RELAXED, __HIP_MEMORY_SCOPE_AGENT);
                sM[it >> 5][it & 31] = a;
            }
        }
        __syncthreads();

        // stage D: apply (row-local): integ via Horner + skip GEMM (+ gelu)
        for (int rr = r0; rr < RPB; rr += 16) {
            const float xn = xrow[rr];
            float Ph = sM[KT - 1][c];
#pragma unroll
            for (int k = KT - 2; k >= 0; k--) Ph = fmaf(Ph, xn, sM[k][c]);
            const float integ = sig2 * EXP2F(xn * xn * nb2) * Ph;
            float skip = p.pw_b[l * CH + c];
#pragma unroll
            for (int k = 0; k < CH; k++) skip = fmaf(fqb[cur][rr][k], sWt[l][k][c], skip);
            float v = skip + integ;
            if (l < 2) v = gelu_tanh(v);
            fqb[cur ^ 1][rr][c] = v;
        }
        cur ^= 1;
    }
    __syncthreads();

    // ---- projection head (row-local; reuse sS/sLT) ----
    for (int rr = r0; rr < RPB; rr += 16) {
        float s = sb1[c];
#pragma unroll
        for (int k = 0; k < CH; k++) s = fmaf(fqb[cur][rr][k], sW1t[k][c], s);
        sS[rr][c] = gelu_tanh(s);
    }
    __syncthreads();
    for (int rr = r0; rr < RPB; rr += 16) {
        float s = sb2[c];
#pragma unroll
        for (int k = 0; k < CH; k++) s = fmaf(sS[rr][k], sW2t[k][c], s);
        sLT[rr][c] = gelu_tanh(s);
    }
    __syncthreads();
    if (tid < RPB) {
        float s = p.p3b[0];
#pragma unroll
        for (int k = 0; k < CH; k++) s = fmaf(sLT[tid][k], sW3v[k], s);
        p.out[n0 + tid] = s;
    }
}

extern "C" void kernel_launch(void* const* d_in, const int* in_sizes, int n_in,
                              void* d_out, int out_size, void* d_ws, size_t ws_size,
                              hipStream_t stream) {
    Params p;
    p.f_x    = (const float*)d_in[0];
    p.x_grid = (const float*)d_in[1];
    p.qw     = (const float*)d_in[2];
    p.lift_W = (const float*)d_in[3];
    p.lift_b = (const float*)d_in[4];
    p.pw_W   = (const float*)d_in[5];
    p.pw_b   = (const float*)d_in[6];
    p.kle    = (const float*)d_in[7];
    p.kls    = (const float*)d_in[8];
    p.p1W    = (const float*)d_in[9];
    p.p1b    = (const float*)d_in[10];
    p.p2W    = (const float*)d_in[11];
    p.p2b    = (const float*)d_in[12];
    p.p3W    = (const float*)d_in[13];
    p.p3b    = (const float*)d_in[14];

    p.ctrl   = (int*)d_ws;
    p.P      = (float*)((char*)d_ws + 256);
    p.out    = (float*)d_out;

    // zero the barrier counters each call (capture-legal async memset)
    hipMemsetAsync(d_ws, 0, 256, stream);
    k_fused<<<dim3(NBLK), dim3(NTHR), 0, stream>>>(p);
}